// Round 12
// baseline (235.583 us; speedup 1.0000x reference)
//
#include <hip/hip_runtime.h>

#define Bn 4
#define Cn 64
#define Hn 128
#define Wn 128
#define HWn (Hn*Wn)          // 16384
#define NPIX (Bn*HWn)        // 65536
#define KKn 9
#define NOFF 18
#define EPSf 1e-5f

// ws layout (float-word offsets)
#define OFF_DWT   0u              // f32 [p][c], 4194304 words
#define OFF_XTH   4194304u        // bf16 [p][c], 2097152 words
#define OFF_GEOM  6291456u        // f32 [kk][p][2], 1179648 words
#define OFF_WT    7471104u        // bf16 [kk][o][c], 36864 words
#define OFF_SSUM  7507968u
#define OFF_SSQ   7508032u

typedef __attribute__((ext_vector_type(8))) short short8v;
typedef __attribute__((ext_vector_type(8))) unsigned short ushort8v;
typedef __attribute__((ext_vector_type(4))) float float4v;

__device__ __forceinline__ unsigned short f2bf(float f) {
  unsigned u = __builtin_bit_cast(unsigned, f);
  u += 0x7fffu + ((u >> 16) & 1u);
  return (unsigned short)(u >> 16);
}
__device__ __forceinline__ float b2f(unsigned short u) {
  return __builtin_bit_cast(float, ((unsigned)u) << 16);
}

#define MKADDR(GG, B00, B01, B10, B11, M00, M01, M10, M11)                    \
  {                                                                           \
    float py_ = (GG).x, px_ = (GG).y;                                         \
    float y0f_ = floorf(py_), x0f_ = floorf(px_);                             \
    float wy_ = py_ - y0f_, wx_ = px_ - x0f_;                                 \
    int y0_ = (int)y0f_, x0_ = (int)x0f_;                                     \
    int y1_ = y0_ + 1, x1_ = x0_ + 1;                                         \
    bool vy0_ = (y0_ >= 0) && (y0_ < Hn), vy1_ = (y1_ >= 0) && (y1_ < Hn);    \
    bool vx0_ = (x0_ >= 0) && (x0_ < Wn), vx1_ = (x1_ >= 0) && (x1_ < Wn);    \
    int y0c_ = vy0_ ? y0_ : 0, y1c_ = vy1_ ? y1_ : 0;                         \
    int x0c_ = vx0_ ? x0_ : 0, x1c_ = vx1_ ? x1_ : 0;                         \
    M00 = (vy0_ && vx0_) ? (1.f - wy_) * (1.f - wx_) : 0.f;                   \
    M01 = (vy0_ && vx1_) ? (1.f - wy_) * wx_ : 0.f;                           \
    M10 = (vy1_ && vx0_) ? wy_ * (1.f - wx_) : 0.f;                           \
    M11 = (vy1_ && vx1_) ? wy_ * wx_ : 0.f;                                   \
    B00 = xb + (size_t)((y0c_ * Wn + x0c_) * 64);                             \
    B01 = xb + (size_t)((y0c_ * Wn + x1c_) * 64);                             \
    B10 = xb + (size_t)((y1c_ * Wn + x0c_) * 64);                             \
    B11 = xb + (size_t)((y1c_ * Wn + x1c_) * 64);                             \
  }

// ---------------------------------------------------------------------------
// K1v6: depthwise 3x3 + bias -> DWT f32 / XTH bf16 (NHWC), BN stats fused.
// 2048 blocks x 256 thr; thread = (32-px slab, 8-ch group) -> 32 waves/CU cap.
__global__ __launch_bounds__(256) void k1_dw_t5(
    const float* __restrict__ x, const float* __restrict__ dw_w,
    const float* __restrict__ dw_b, unsigned short* __restrict__ XTH,
    float* __restrict__ DWT, float* __restrict__ ssum, float* __restrict__ ssq)
{
  __shared__ float lds_dw[32][65];
  __shared__ float lds_xt[32][65];
  const int t = threadIdx.x;
  const int pxl = t & 31;
  const int cg = t >> 5;                 // 0..7 -> 8-channel group
  const int p = blockIdx.x * 32 + pxl;
  const int b = p >> 14; const int sp = p & 16383;
  const int h = sp >> 7; const int w = sp & 127;

  int so[9]; float mval[9];
  #pragma unroll
  for (int tt = 0; tt < 9; tt++) {
    int dy = tt / 3 - 1, dx = tt % 3 - 1;
    int hh = h + dy, ww = w + dx;
    bool v = (hh >= 0) && (hh < Hn) && (ww >= 0) && (ww < Wn);
    int hc = v ? hh : h; int wc = v ? ww : w;
    so[tt] = hc * Wn + wc;
    mval[tt] = v ? 1.f : 0.f;
  }
  const float* xb = x + (size_t)b * Cn * HWn;

  #pragma unroll
  for (int j = 0; j < 8; j++) {
    int c = cg * 8 + j;
    const float* xc = xb + (size_t)c * HWn;
    float acc = dw_b[c];
    #pragma unroll
    for (int tt = 0; tt < 9; tt++)
      acc += (mval[tt] * xc[so[tt]]) * dw_w[c * 9 + tt];
    lds_dw[pxl][c] = acc;
    lds_xt[pxl][c] = xc[sp];
  }
  __syncthreads();

  // DWT flush: 2 passes x (16 px x 16 lanes float4)
  #pragma unroll
  for (int k = 0; k < 2; k++) {
    int px_l = k * 16 + (t >> 4);
    int c_l  = (t & 15) * 4;
    float4 v = *(float4*)&lds_dw[px_l][c_l];
    size_t pp = (size_t)blockIdx.x * 32 + px_l;
    *(float4*)&DWT[pp * 64 + c_l] = v;
  }
  // XTH flush: 1 pass: 32 px x 8 lanes x uint4
  {
    int px_l = t >> 3;
    int cg8  = (t & 7) * 8;
    unsigned pk[4];
    #pragma unroll
    for (int j = 0; j < 4; j++) {
      unsigned short lo = f2bf(lds_xt[px_l][cg8 + 2 * j]);
      unsigned short hi = f2bf(lds_xt[px_l][cg8 + 2 * j + 1]);
      pk[j] = (unsigned)lo | ((unsigned)hi << 16);
    }
    size_t pp = (size_t)blockIdx.x * 32 + px_l;
    *(uint4*)&XTH[pp * 64 + cg8] = make_uint4(pk[0], pk[1], pk[2], pk[3]);
  }

  // fused BN stats: thread (c = t&63, grp = t>>6) sums 8 px
  int cc = t & 63, grp = t >> 6;
  float s = 0.f, q = 0.f;
  #pragma unroll
  for (int i = 0; i < 8; i++) {
    float v = lds_dw[grp * 8 + i][cc];
    s += v; q += v * v;
  }
  __syncthreads();
  float* scratch = &lds_xt[0][0];
  scratch[t] = s; scratch[256 + t] = q;
  __syncthreads();
  if (t < 64) {
    float s0 = scratch[t] + scratch[t + 64] + scratch[t + 128] + scratch[t + 192];
    float q0 = scratch[256 + t] + scratch[256 + t + 64] +
               scratch[256 + t + 128] + scratch[256 + t + 192];
    atomicAdd(&ssum[t], s0);
    atomicAdd(&ssq[t], q0);
  }
}

// ---------------------------------------------------------------------------
__global__ __launch_bounds__(256) void k_wt(const float* __restrict__ dwf,
                                            unsigned short* __restrict__ WT2)
{
  int t = blockIdx.x * 256 + threadIdx.x;
  if (t >= 64 * 64 * 9) return;
  int c = t & 63; int o = (t >> 6) & 63; int kk = t >> 12;
  WT2[t] = f2bf(dwf[(o * 64 + c) * 9 + kk]);
}

// ---------------------------------------------------------------------------
// K3v3: BN finalize head; channel-split halves + LDS reduce -> GEOM2[kk][p][2]
__global__ __launch_bounds__(256) void k3_offsets3(const float* __restrict__ DWT,
    const float* __restrict__ ssum, const float* __restrict__ ssq,
    const float* __restrict__ gamma, const float* __restrict__ beta,
    const float* __restrict__ pw_w, const float* __restrict__ pw_b,
    float* __restrict__ GEOM2)
{
  __shared__ float s_sc[64], s_sh[64];
  __shared__ float s_par[128][NOFF + 1];
  int t = threadIdx.x;
  if (t < 64) {
    float n = (float)NPIX;
    float mean = ssum[t] / n;
    float var = ssq[t] / n - mean * mean;
    float sc = gamma[t] * rsqrtf(var + EPSf);
    s_sc[t] = sc;
    s_sh[t] = beta[t] - mean * sc;
  }
  __syncthreads();

  int pxl = t & 127; int hf = t >> 7;          // channel half
  int p = blockIdx.x * 128 + pxl;
  int sp = p & 16383; int h = sp >> 7; int w = sp & 127;
  float off[NOFF];
  #pragma unroll
  for (int o = 0; o < NOFF; o++) off[o] = hf ? 0.f : pw_b[o];
  const float4* dp = (const float4*)(DWT + (size_t)p * 64);
  #pragma unroll
  for (int c4i = 0; c4i < 8; c4i++) {
    int c4 = hf * 8 + c4i;
    float4 d = dp[c4];
    int c = c4 * 4;
    float x0 = d.x * s_sc[c]     + s_sh[c];
    float x1 = d.y * s_sc[c + 1] + s_sh[c + 1];
    float x2 = d.z * s_sc[c + 2] + s_sh[c + 2];
    float x3 = d.w * s_sc[c + 3] + s_sh[c + 3];
    #pragma unroll
    for (int o = 0; o < NOFF; o++) {
      const float* pw = pw_w + o * 64 + c;
      off[o] += pw[0] * x0 + pw[1] * x1 + pw[2] * x2 + pw[3] * x3;
    }
  }
  if (hf == 1) {
    #pragma unroll
    for (int o = 0; o < NOFF; o++) s_par[pxl][o] = off[o];
  }
  __syncthreads();
  if (hf == 0) {
    #pragma unroll
    for (int o = 0; o < NOFF; o++) off[o] += s_par[pxl][o];
    #pragma unroll
    for (int kk = 0; kk < KKn; kk++) {
      float py = (float)h - 1.f + (float)(kk / 3) + off[2 * kk];
      float px = (float)w - 1.f + (float)(kk % 3) + off[2 * kk + 1];
      float2* g = (float2*)(GEOM2 + ((size_t)kk * NPIX + p) * 2);
      *g = make_float2(py, px);
    }
  }
}

// ---------------------------------------------------------------------------
// k-loop for K4v7: simple rolled body (TLP hides latency), GEOM prefetch d1.
template<int KB, int KE>
__device__ __forceinline__ void kloop(
    const unsigned short* __restrict__ xb, const float* __restrict__ GEOM2,
    const unsigned short* __restrict__ WT2, int pw0, int l15, int c8,
    float4v& acc0, float4v& acc1, float4v& acc2, float4v& acc3)
{
  float2 g = *(const float2*)(GEOM2 + ((size_t)KB * NPIX + pw0 + l15) * 2);
  #pragma unroll
  for (int kk = KB; kk < KE; kk++) {
    float m00, m01, m10, m11;
    const unsigned short *pb00, *pb01, *pb10, *pb11;
    MKADDR(g, pb00, pb01, pb10, pb11, m00, m01, m10, m11);
    if (kk + 1 < KE)
      g = *(const float2*)(GEOM2 + ((size_t)(kk + 1) * NPIX + pw0 + l15) * 2);
    ushort8v u0a = *(const ushort8v*)(pb00 + c8);
    ushort8v u0b = *(const ushort8v*)(pb01 + c8);
    ushort8v u0c = *(const ushort8v*)(pb10 + c8);
    ushort8v u0d = *(const ushort8v*)(pb11 + c8);
    ushort8v u1a = *(const ushort8v*)(pb00 + 32 + c8);
    ushort8v u1b = *(const ushort8v*)(pb01 + 32 + c8);
    ushort8v u1c = *(const ushort8v*)(pb10 + 32 + c8);
    ushort8v u1d = *(const ushort8v*)(pb11 + 32 + c8);
    short8v af0, af1;
    #pragma unroll
    for (int j = 0; j < 8; j++) {
      float s0 = b2f(u0a[j]) * m00 + b2f(u0b[j]) * m01 +
                 b2f(u0c[j]) * m10 + b2f(u0d[j]) * m11;
      af0[j] = (short)f2bf(s0);
      float s1 = b2f(u1a[j]) * m00 + b2f(u1b[j]) * m01 +
                 b2f(u1c[j]) * m10 + b2f(u1d[j]) * m11;
      af1[j] = (short)f2bf(s1);
    }
    const unsigned short* wtkk = WT2 + (size_t)kk * 4096 + (size_t)l15 * 64 + c8;
    {
      short8v ba = *(const short8v*)(wtkk);
      short8v bb = *(const short8v*)(wtkk + 32);
      acc0 = __builtin_amdgcn_mfma_f32_16x16x32_bf16(af0, ba, acc0, 0, 0, 0);
      acc0 = __builtin_amdgcn_mfma_f32_16x16x32_bf16(af1, bb, acc0, 0, 0, 0);
    }
    {
      short8v ba = *(const short8v*)(wtkk + 16 * 64);
      short8v bb = *(const short8v*)(wtkk + 16 * 64 + 32);
      acc1 = __builtin_amdgcn_mfma_f32_16x16x32_bf16(af0, ba, acc1, 0, 0, 0);
      acc1 = __builtin_amdgcn_mfma_f32_16x16x32_bf16(af1, bb, acc1, 0, 0, 0);
    }
    {
      short8v ba = *(const short8v*)(wtkk + 32 * 64);
      short8v bb = *(const short8v*)(wtkk + 32 * 64 + 32);
      acc2 = __builtin_amdgcn_mfma_f32_16x16x32_bf16(af0, ba, acc2, 0, 0, 0);
      acc2 = __builtin_amdgcn_mfma_f32_16x16x32_bf16(af1, bb, acc2, 0, 0, 0);
    }
    {
      short8v ba = *(const short8v*)(wtkk + 48 * 64);
      short8v bb = *(const short8v*)(wtkk + 48 * 64 + 32);
      acc3 = __builtin_amdgcn_mfma_f32_16x16x32_bf16(af0, ba, acc3, 0, 0, 0);
      acc3 = __builtin_amdgcn_mfma_f32_16x16x32_bf16(af1, bb, acc3, 0, 0, 0);
    }
  }
}

// ---------------------------------------------------------------------------
// K4v7: block = 16 px x 2 kk-split waves (0: kk0-4, 1: kk5-8); LDS exchange;
// each wave epilogues 2 n-tiles. 4096 blocks -> 8192 waves (100% ceiling).
__global__ __launch_bounds__(128) void k4_mfma7(
    const unsigned short* __restrict__ XTH, const float* __restrict__ DWT,
    const float* __restrict__ GEOM2, const unsigned short* __restrict__ WT2,
    const float* __restrict__ ssum, const float* __restrict__ ssq,
    const float* __restrict__ gamma, const float* __restrict__ beta,
    const float* __restrict__ deform_b, const float* __restrict__ skip_scale,
    float* __restrict__ out)
{
  __shared__ float s_sc[64], s_sh[64];
  __shared__ float s_xch[2][64][9];
  const int tid = threadIdx.x;
  if (tid < 64) {
    float n = (float)NPIX;
    float mean = ssum[tid] / n;
    float var = ssq[tid] / n - mean * mean;
    float sc = gamma[tid] * rsqrtf(var + EPSf);
    s_sc[tid] = sc;
    s_sh[tid] = beta[tid] - mean * sc;
  }
  __syncthreads();

  const int lane = tid & 63;
  const int wv = tid >> 6;
  const int l15 = lane & 15;
  const int lg = lane >> 4;
  const int bid = blockIdx.x;
  const int swz = (bid & 7) * 512 + (bid >> 3);   // 4096 % 8 == 0 -> bijective
  const int pw0 = swz * 16;
  const int b = pw0 >> 14;

  float4v acc0 = {0.f,0.f,0.f,0.f}, acc1 = {0.f,0.f,0.f,0.f};
  float4v acc2 = {0.f,0.f,0.f,0.f}, acc3 = {0.f,0.f,0.f,0.f};

  const unsigned short* xb = XTH + (size_t)b * HWn * 64;
  const int c8 = lg * 8;

  if (wv == 0)
    kloop<0, 5>(xb, GEOM2, WT2, pw0, l15, c8, acc0, acc1, acc2, acc3);
  else
    kloop<5, 9>(xb, GEOM2, WT2, pw0, l15, c8, acc0, acc1, acc2, acc3);

  // exchange: each wave donates the half the other wave will write out
  if (wv == 0) {
    #pragma unroll
    for (int r = 0; r < 4; r++) {
      s_xch[0][lane][r] = acc2[r]; s_xch[0][lane][4 + r] = acc3[r];
    }
  } else {
    #pragma unroll
    for (int r = 0; r < 4; r++) {
      s_xch[1][lane][r] = acc0[r]; s_xch[1][lane][4 + r] = acc1[r];
    }
  }
  __syncthreads();

  float sk = skip_scale[0];
#define EPI(NT, A)                                                            \
  { int o = (NT) * 16 + l15;                                                  \
    float sc_ = s_sc[o], sh_ = s_sh[o], db_ = deform_b[o];                    \
    float* outb = out + ((size_t)(b * 64 + o)) * HWn;                         \
    _Pragma("unroll")                                                         \
    for (int r = 0; r < 4; r++) {                                             \
      int pp = pw0 + lg * 4 + r; int sp = pp & 16383;                         \
      float dv = DWT[(size_t)pp * 64 + o];                                    \
      float xv = b2f(XTH[(size_t)pp * 64 + o]);                               \
      outb[sp] = A[r] + db_ + dv * sc_ + sh_ + xv * sk; } }

  if (wv == 0) {
    #pragma unroll
    for (int r = 0; r < 4; r++) {
      acc0[r] += s_xch[1][lane][r]; acc1[r] += s_xch[1][lane][4 + r];
    }
    EPI(0, acc0); EPI(1, acc1);
  } else {
    #pragma unroll
    for (int r = 0; r < 4; r++) {
      acc2[r] += s_xch[0][lane][r]; acc3[r] += s_xch[0][lane][4 + r];
    }
    EPI(2, acc2); EPI(3, acc3);
  }
#undef EPI
}

// ---------------------------------------------------------------------------
extern "C" void kernel_launch(void* const* d_in, const int* in_sizes, int n_in,
                              void* d_out, int out_size, void* d_ws, size_t ws_size,
                              hipStream_t stream)
{
  const float* x        = (const float*)d_in[0];
  const float* dw_w     = (const float*)d_in[1];
  const float* dw_b     = (const float*)d_in[2];
  const float* bn_gamma = (const float*)d_in[3];
  const float* bn_beta  = (const float*)d_in[4];
  const float* pw_w     = (const float*)d_in[5];
  const float* pw_b     = (const float*)d_in[6];
  const float* skip     = (const float*)d_in[7];
  const float* deform_w = (const float*)d_in[8];
  const float* deform_b = (const float*)d_in[9];
  float* out = (float*)d_out;
  float* ws  = (float*)d_ws;

  unsigned short* XTH = (unsigned short*)(ws + OFF_XTH);
  unsigned short* WT2 = (unsigned short*)(ws + OFF_WT);

  hipMemsetAsync(ws + OFF_SSUM, 0, 2 * 64 * sizeof(float), stream);

  k_wt<<<144, 256, 0, stream>>>(deform_w, WT2);
  k1_dw_t5<<<2048, 256, 0, stream>>>(x, dw_w, dw_b, XTH, ws + OFF_DWT,
                                     ws + OFF_SSUM, ws + OFF_SSQ);
  k3_offsets3<<<512, 256, 0, stream>>>(ws + OFF_DWT, ws + OFF_SSUM, ws + OFF_SSQ,
                                       bn_gamma, bn_beta, pw_w, pw_b, ws + OFF_GEOM);
  k4_mfma7<<<4096, 128, 0, stream>>>(XTH, ws + OFF_DWT, ws + OFF_GEOM, WT2,
                                     ws + OFF_SSUM, ws + OFF_SSQ, bn_gamma, bn_beta,
                                     deform_b, skip, out);
}